// Round 8
// baseline (288.598 us; speedup 1.0000x reference)
//
#include <hip/hip_runtime.h>
#include <hip/hip_fp16.h>

#define Bb 4
#define Nn 20000
#define Ee 320000
#define CIN 32
#define COUT 32
#define Kk 16
#define Mm 2
#define EPB (Ee / 64)   /* 5000 super-iters (64 instances) per (b,m) slice */
#define WPB 1024        /* waves per (b,m): (2048/8) blocks * 4 waves */
#define PSLICE ((size_t)Bb * Nn)   /* rows per XCD partial */

typedef __attribute__((ext_vector_type(8))) short short8;
typedef __attribute__((ext_vector_type(4))) float f32x4;

__device__ __forceinline__ unsigned f2bf(float x) {   // round-half-up bf16 bits
    union { float f; unsigned u; } c; c.f = x;
    return (c.u + 0x8000u) >> 16;
}

// L2-local (no sc1) packed fp16 atomic add: executes at the issuing XCD's TCC.
__device__ __forceinline__ void l2_pk_add_f16(__half* p, __half2 v) {
    union { __half2 h; unsigned u; } cv; cv.h = v;
    asm volatile("global_atomic_pk_add_f16 %0, %1, off"
                 :: "v"((unsigned long long)(uintptr_t)p), "v"(cv.u) : "memory");
}

// ---------------- kernel 1: prep
//  A: transpose f -> fTp[node][pair c] = (f[c], f[c+16]) float2
//  C: pack pbh[b][m][node][32 bf16] = [bc k0..15 | bs k0..15]
//  B/D: zero 8 XCD partials (41 MB); pack pn = (node.xy, nv.xy)
__global__ __launch_bounds__(256) void prep_fused(
    const float* __restrict__ f,
    const float4* __restrict__ bc4,
    const float4* __restrict__ bs4,
    const float* __restrict__ nodes,
    const float* __restrict__ nrm,
    float* __restrict__ fTp,
    float4* __restrict__ partz,       // partials viewed as float4 for zeroing
    unsigned short* __restrict__ pbh,
    float4* __restrict__ pn) {
    __shared__ float ldsT[32 * 33];
    __shared__ float ldc[32 * 33];
    __shared__ float ldss[32 * 33];
    const int t   = threadIdx.x;
    const int blk = blockIdx.x;            // 2500 blocks
    const int b   = blk / 625;
    const int n0  = (blk % 625) * 32;
    // phase A: 32x32 transpose tile -> interleaved pair layout
    {
        int lane = t & 31, grp = t >> 5;
        #pragma unroll
        for (int r = 0; r < 4; ++r)
            ldsT[(grp + r * 8) * 33 + lane] = f[(b * CIN + grp + r * 8) * Nn + n0 + lane];
        __syncthreads();
        #pragma unroll
        for (int r = 0; r < 4; ++r) {
            int nl = grp + r * 8;
            // channel = lane -> slot (lane&15)*2 + (lane>>4)
            fTp[((size_t)(b * Nn + n0 + nl)) * CIN + (lane & 15) * 2 + (lane >> 4)]
                = ldsT[lane * 33 + nl];
        }
    }
    // phase C: pack 32 nodes to bf16 rows
    {
        int nl = t >> 3, j4 = t & 7;
        float4 vc = bc4[(b * Nn + n0 + nl) * 8 + j4];
        float4 vs = bs4[(b * Nn + n0 + nl) * 8 + j4];
        float* pc = ldc + nl * 33 + 4 * j4;
        pc[0] = vc.x; pc[1] = vc.y; pc[2] = vc.z; pc[3] = vc.w;
        float* ps = ldss + nl * 33 + 4 * j4;
        ps[0] = vs.x; ps[1] = vs.y; ps[2] = vs.z; ps[3] = vs.w;
        __syncthreads();
        int u = t & 3, mm = (t >> 2) & 1;           // nl = t>>3
        const float* src = (u < 2) ? (ldc + nl * 33) : (ldss + nl * 33);
        int k0 = (u & 1) * 8;
        unsigned o[4];
        #pragma unroll
        for (int i = 0; i < 4; ++i) {
            float v0 = src[2 * (k0 + 2 * i) + mm];
            float v1 = src[2 * (k0 + 2 * i + 1) + mm];
            o[i] = f2bf(v0) | ((__float_as_uint(v1) + 0x8000u) & 0xffff0000u);
        }
        uint4 ov = make_uint4(o[0], o[1], o[2], o[3]);
        *(uint4*)(pbh + ((size_t)((b * 2 + mm) * Nn + n0 + nl)) * 32 + 8 * u) = ov;
    }
    // phase B/D: grid-stride
    const int t0 = blk * 256 + t, S = 2500 * 256;
    // partials: 8 * Bb*Nn*32 halves = 41 MB = 2,560,000 float4
    for (int i = t0; i < 2560000; i += S) partz[i] = make_float4(0, 0, 0, 0);
    for (int i = t0; i < Bb * Nn; i += S) {
        float2 nd = ((const float2*)nodes)[i];
        float2 nv = ((const float2*)nrm)[i];
        pn[i] = make_float4(nd.x, nd.y, nv.x, nv.y);
    }
}

// ---------------- kernel 2: edge scatter; MFMA matvec; L2-local pk-fp16 atomics
// into per-physical-XCD partials (XCC_ID-indexed -> scheduler-independent).
__global__ __launch_bounds__(256, 4) void edge_kernel(
    const uint4* __restrict__ pbh4,
    const float4* __restrict__ pn,
    const float2* __restrict__ fTp2,
    const int4* __restrict__ de4,
    const float* __restrict__ nwt,
    const float* __restrict__ wc,
    const float* __restrict__ wsp,
    const float* __restrict__ w0,
    __half* __restrict__ partials) {
    __shared__ __align__(16) unsigned spb[4][16 * 36];   // 9216 B
    const int t  = threadIdx.x;
    const int wv = t >> 6;
    const int l  = t & 63;
    const int c  = l & 15;
    const int q  = l >> 4;
    const int kb = (q & 1) * 8;
    const int mode = q >> 1;
    const unsigned smask = mode ? 0x80000000u : 0u;
    const int bm = blockIdx.x & 7;
    const int b  = bm >> 1, m = bm & 1;
    const int wid = (blockIdx.x >> 3) * 4 + wv;       // 0..1023
    const int rowoff = (b + m) * Nn;                  // bt -> pbh row base add

    unsigned xcc;
    asm("s_getreg_b32 %0, hwreg(HW_REG_XCC_ID)" : "=s"(xcc));
    __half* mypart = partials + (size_t)(xcc & 7) * PSLICE * 32;

    // loop-invariant B fragments (weights, bf16): B[k=q*8+j][ch]
    short8 bf0, bf1;
    #pragma unroll
    for (int j = 0; j < 8; ++j) {
        int k = q * 8 + j;
        float w0v, w1v;
        if (k < 16) {
            w0v = 2.0f * wc[(c * Kk + k) * Mm + m];
            w1v = 2.0f * wc[((c + 16) * Kk + k) * Mm + m];
        } else {
            w0v = 2.0f * wsp[(c * Kk + (k - 16)) * Mm + m];
            w1v = 2.0f * wsp[((c + 16) * Kk + (k - 16)) * Mm + m];
        }
        bf0[j] = (short)f2bf(w0v);
        bf1[j] = (short)f2bf(w1v);
    }
    const float acc00 = w0[c * Mm + m] + 1.0f;
    const float acc01 = w0[(c + 16) * Mm + m] + 1.0f;

    unsigned* myld = spb[wv];
    const int il = l >> 2, jj4 = l & 3;
    const int ceven = ((c & 1) == 0);
    const int choff = ceven ? c : (c + 15);

    // pipeline state
    float scale; int bt, bs;
    uint4 h0, h1;                        // prefetched pbh rows (t / s chunks)
    float2 fp[4];                        // prefetched fs pairs
    int4  d4n;
    int   btn, bsn;
    float dxn, dyn, nzn, nwn2, nwn;

    int s = wid;
    {
        int e = s * 64 + l;
        int4 d4 = de4[b * Ee + e];
        int tn = m ? d4.y : d4.x;
        int sn = m ? d4.w : d4.z;
        bt = b * Nn + tn;
        bs = b * Nn + sn;
        float4 qt = pn[bt];
        float4 qs = pn[bs];
        float dx = qt.x - qs.x, dy = qt.y - qs.y;
        float r2 = dx * dx + dy * dy + 1e-6f;
        scale = nwt[(b * Ee + e) * Mm + m] * (dx * qs.z + dy * qs.w) / r2;
        int bta = __shfl(bt, il), bsa = __shfl(bs, il);
        h0 = pbh4[(size_t)(bta + rowoff) * 4 + jj4];
        h1 = pbh4[(size_t)(bsa + rowoff) * 4 + jj4];
        #pragma unroll
        for (int r = 0; r < 4; ++r) {
            int bsr = __shfl(bs, 4 * q + r);
            fp[r] = fTp2[(size_t)bsr * 16 + c];
        }
    }

    for (; s < EPB; s += WPB) {
        const bool last = (s + WPB >= EPB);
        #pragma unroll
        for (int tau = 0; tau < 4; ++tau) {
            // ---- 1. commit prefetched pbh rows to LDS
            unsigned* row = myld + il * 36;
            *(uint4*)(row + 4 * jj4)      = h0;
            *(uint4*)(row + 16 + 4 * jj4) = h1;

            // ---- 2. A-frag: bf16 expand + products + MFMA (R3-verified math)
            const unsigned* rr = myld + c * 36;
            uint4 ut = *(const uint4*)(rr + (kb >> 1));
            uint4 us = *(const uint4*)(rr + 8 + (kb >> 1));
            uint4 ux = *(const uint4*)(rr + 16 + (mode ? 8 : 0) + (kb >> 1));
            uint4 uy = *(const uint4*)(rr + 16 + (mode ? 0 : 8) + (kb >> 1));
            unsigned utA[4] = {ut.x, ut.y, ut.z, ut.w};
            unsigned usA[4] = {us.x, us.y, us.z, us.w};
            unsigned uxA[4] = {ux.x, ux.y, ux.z, ux.w};
            unsigned uyA[4] = {uy.x, uy.y, uy.z, uy.w};

            union { short8 s8; unsigned u[4]; } af;
            #pragma unroll
            for (int jp = 0; jp < 4; ++jp) {
                float t0 = __uint_as_float(utA[jp] << 16);
                float t1 = __uint_as_float(utA[jp] & 0xffff0000u);
                float b0 = __uint_as_float((usA[jp] << 16) ^ smask);
                float b1 = __uint_as_float((usA[jp] & 0xffff0000u) ^ smask);
                float x0 = __uint_as_float(uxA[jp] << 16);
                float x1 = __uint_as_float(uxA[jp] & 0xffff0000u);
                float y0 = __uint_as_float(uyA[jp] << 16);
                float y1 = __uint_as_float(uyA[jp] & 0xffff0000u);
                float v0f = fmaf(t0, x0, b0 * y0);
                float v1f = fmaf(t1, x1, b1 * y1);
                af.u[jp] = f2bf(v0f) | ((__float_as_uint(v1f) + 0x8000u) & 0xffff0000u);
            }
            f32x4 zero = {0.f, 0.f, 0.f, 0.f};
            f32x4 d0 = __builtin_amdgcn_mfma_f32_16x16x32_bf16(af.s8, bf0, zero, 0, 0, 0);
            f32x4 d1 = __builtin_amdgcn_mfma_f32_16x16x32_bf16(af.s8, bf1, zero, 0, 0, 0);

            // ---- 3. epilogue values (consume fp BEFORE prefetch overwrites)
            float val0[4], val1[4];
            int   btr[4];
            #pragma unroll
            for (int r = 0; r < 4; ++r) {
                int srcl = tau * 16 + 4 * q + r;
                float sc = __shfl(scale, srcl);
                btr[r]   = __shfl(bt, srcl);
                val0[r] = (acc00 + d0[r]) * fp[r].x * sc;
                val1[r] = (acc01 + d1[r]) * fp[r].y * sc;
            }

            // ---- 4. geometry pipeline for next super-iter
            if (tau == 1 && !last)
                d4n = de4[b * Ee + (s + WPB) * 64 + l];
            if (tau == 2 && !last) {
                int tn = m ? d4n.y : d4n.x;
                int sn = m ? d4n.w : d4n.z;
                btn = b * Nn + tn;
                bsn = b * Nn + sn;
                float4 qt = pn[btn];
                float4 qs = pn[bsn];
                dxn = qt.x - qs.x; dyn = qt.y - qs.y;
                nzn = qs.z; nwn2 = qs.w;
                nwn = nwt[(b * Ee + (s + WPB) * 64 + l) * Mm + m];
            }

            // ---- 5. prefetch next tile (pbh rows + fs pairs) BEFORE atomics
            if (tau < 3 || !last) {
                int ntau;
                if (tau == 3) {
                    float r2 = dxn * dxn + dyn * dyn + 1e-6f;
                    scale = nwn * (dxn * nzn + dyn * nwn2) / r2;
                    bt = btn; bs = bsn;
                    ntau = 0;
                } else {
                    ntau = tau + 1;
                }
                int srcA = ntau * 16 + il;
                int bta = __shfl(bt, srcA), bsa = __shfl(bs, srcA);
                h0 = pbh4[(size_t)(bta + rowoff) * 4 + jj4];
                h1 = pbh4[(size_t)(bsa + rowoff) * 4 + jj4];
                #pragma unroll
                for (int r = 0; r < 4; ++r) {
                    int bsr = __shfl(bs, ntau * 16 + 4 * q + r);
                    fp[r] = fTp2[(size_t)bsr * 16 + c];
                }
            }

            // ---- 6. L2-local pk-fp16 atomics into this XCD's partial
            __builtin_amdgcn_sched_barrier(0);
            #pragma unroll
            for (int r = 0; r < 4; ++r) {
                float n0 = __shfl_xor(val0[r], 1);
                float n1 = __shfl_xor(val1[r], 1);
                __half2 hv = ceven ? __floats2half2_rn(val0[r], n0)
                                   : __floats2half2_rn(n1, val1[r]);
                l2_pk_add_f16(mypart + (size_t)btr[r] * CIN + choff, hv);
            }
        }
    }
}

// ---------------- kernel 3: out[b,o,n] = bias[o] + sum_i wk[o,i] * sum_x partial[x][b,n,i]
__global__ __launch_bounds__(256) void out_kernel(
    const float4* __restrict__ part4,     // fp16 partials as float4 (8 halves)
    const float* __restrict__ wk,
    const float* __restrict__ bias,
    float* __restrict__ out) {
    __shared__ float lwk[1024];
    __shared__ float lf[64 * 33];
    int blk  = blockIdx.x;
    int b    = blk / 313;
    int tile = blk % 313;
    int n0   = tile * 64;
    int t    = threadIdx.x;
    #pragma unroll
    for (int r = 0; r < 4; ++r) lwk[r * 256 + t] = wk[r * 256 + t];
    {
        int nl = t >> 2, i8 = t & 3;      // 64 nodes x 4 chunks of 8 halves
        int n  = n0 + nl;
        float acc8[8] = {0, 0, 0, 0, 0, 0, 0, 0};
        if (n < Nn) {
            #pragma unroll
            for (int x = 0; x < 8; ++x) {
                union { float4 v; __half2 h[4]; } u;
                u.v = part4[((size_t)x * PSLICE + (size_t)b * Nn + n) * 4 + i8];
                #pragma unroll
                for (int j = 0; j < 4; ++j) {
                    float2 fj = __half22float2(u.h[j]);
                    acc8[2 * j]     += fj.x;
                    acc8[2 * j + 1] += fj.y;
                }
            }
        }
        float* p = lf + nl * 33 + i8 * 8;
        #pragma unroll
        for (int j = 0; j < 8; ++j) p[j] = acc8[j];
    }
    __syncthreads();
    int nl = t & 63;
    int og = t >> 6;
    int n  = n0 + nl;
    if (n < Nn) {
        #pragma unroll
        for (int r = 0; r < 8; ++r) {
            int o = r * 4 + og;
            float acc = bias[o];
            #pragma unroll
            for (int i = 0; i < 32; ++i) acc += lwk[o * 32 + i] * lf[nl * 33 + i];
            out[(b * COUT + o) * Nn + n] = acc;
        }
    }
}

extern "C" void kernel_launch(void* const* d_in, const int* in_sizes, int n_in,
                              void* d_out, int out_size, void* d_ws, size_t ws_size,
                              hipStream_t stream) {
    const float* f       = (const float*)d_in[0];
    const float* bases_c = (const float*)d_in[1];
    const float* bases_s = (const float*)d_in[2];
    const float* nodes   = (const float*)d_in[4];
    const float* nrm     = (const float*)d_in[5];
    const int*   de      = (const int*)d_in[6];
    const float* nwt     = (const float*)d_in[7];
    const float* wc      = (const float*)d_in[8];
    const float* wsp     = (const float*)d_in[9];
    const float* w0      = (const float*)d_in[10];
    const float* wk      = (const float*)d_in[11];
    const float* bias    = (const float*)d_in[12];
    float* out = (float*)d_out;

    float*          fTp  = (float*)d_ws;                       // 2,560,000 f  (10.24 MB)
    unsigned short* pbh  = (unsigned short*)(fTp + 2560000);   // 5,120,000 bf16 (10.24 MB)
    float4*         pn   = (float4*)(pbh + 5120000);           // 80,000 f4   (1.28 MB)
    __half*         part = (__half*)(pn + 80000);              // 8*2,560,000 halves (41 MB)
    // total 62.76 MB

    prep_fused<<<2500, 256, 0, stream>>>(f, (const float4*)bases_c,
                                         (const float4*)bases_s, nodes, nrm,
                                         fTp, (float4*)part, pbh, pn);
    edge_kernel<<<2048, 256, 0, stream>>>((const uint4*)pbh, pn, (const float2*)fTp,
                                          (const int4*)de, nwt, wc, wsp, w0, part);
    out_kernel<<<Bb * 313, 256, 0, stream>>>((const float4*)part, wk, bias, out);
}